// Round 1
// 732.491 us; speedup vs baseline: 1.6052x; 1.6052x over previous
//
#include <hip/hip_runtime.h>

// Grouped conv2d N=16 Cin=256 H=W=128 Cout=512 k=3 groups=16 (Cin/g=16, Cout/g=32, pad=1)
// fp32-accurate via bf16 hi/lo split (3 MFMA passes: hh + hl + lh) on v_mfma_f32_32x32x16_bf16.
// Per block: one (n,g), 8x32 pixel tile, all 32 couts. 4 waves, each wave = 2 rows (2 MFMA tiles).
// LDS x layout: per pixel 64B = 4 chunks {hi ci0-7, hi ci8-15, lo ci0-7, lo ci8-15},
// chunk s stored at slot (s + (p>>1)) & 3  -> bank-conflict-free ds_read_b128 / ds_write_b128.

#define CIN_PG 16
#define COUT_PG 32
#define HH 128
#define WW 128
#define TH 8
#define TW 32
#define XTH (TH + 2)      // 10
#define XTW (TW + 2)      // 34
#define NPX (XTH * XTW)   // 340
#define PLANE (HH * WW)   // 16384

typedef __attribute__((ext_vector_type(8))) short bf16x8;
typedef __attribute__((ext_vector_type(16))) float f32x16;
typedef __attribute__((ext_vector_type(4))) unsigned int u32x4;

__device__ __forceinline__ unsigned bfpack(float a, float b) {
    unsigned ua = __builtin_bit_cast(unsigned, a);
    unsigned ub = __builtin_bit_cast(unsigned, b);
    return (ua >> 16) | (ub & 0xffff0000u);   // elem0 in low half, elem1 in high half
}

// ---- prep: W fp32 [512][16][3][3] -> per (g,tap,co) 64B of bf16 {hi0,hi1,lo0,lo1},
//      chunk s stored at slot (s + ((co>>1)&3)) & 3 (matches A-frag read swizzle).
__global__ __launch_bounds__(256) void prep_weights(
    const float* __restrict__ wgt, unsigned* __restrict__ wks)
{
    int t = blockIdx.x * 256 + threadIdx.x;
    if (t >= 16 * COUT_PG * 9) return;
    int tap = t % 9;
    int co  = (t / 9) % COUT_PG;
    int g   = t / (9 * COUT_PG);
    const float* src = wgt + ((size_t)(g * COUT_PG + co) * CIN_PG * 9) + tap;
    float v[16], lo[16];
#pragma unroll
    for (int ci = 0; ci < 16; ++ci) {
        v[ci] = src[ci * 9];
        unsigned ub = __builtin_bit_cast(unsigned, v[ci]);
        float hf = __builtin_bit_cast(float, ub & 0xffff0000u);
        lo[ci] = v[ci] - hf;   // exact in fp32
    }
    u32x4 c[4];
#pragma unroll
    for (int j = 0; j < 4; ++j) {
        c[0][j] = bfpack(v[2 * j], v[2 * j + 1]);
        c[1][j] = bfpack(v[8 + 2 * j], v[8 + 2 * j + 1]);
        c[2][j] = bfpack(lo[2 * j], lo[2 * j + 1]);
        c[3][j] = bfpack(lo[8 + 2 * j], lo[8 + 2 * j + 1]);
    }
    unsigned* dst = wks + (size_t)((g * 9 + tap) * COUT_PG + co) * 16;
    unsigned rot = (co >> 1) & 3;
#pragma unroll
    for (int s = 0; s < 4; ++s) {
        unsigned slot = (s + rot) & 3;
        *(u32x4*)(dst + slot * 4) = c[s];
    }
}

__global__ __launch_bounds__(256, 3) void grouped_conv_mfma(
    const float* __restrict__ x, const unsigned* __restrict__ wks,
    const float* __restrict__ bias, float* __restrict__ out)
{
    __shared__ unsigned xs[NPX * 16];          // 340 px * 64B = 21760 B
    __shared__ unsigned ws[9 * COUT_PG * 16];  // 18432 B
    __shared__ float bs[COUT_PG];

    const int bx = blockIdx.x;
    const int wtile = bx & 3;
    const int htile = (bx >> 2) & 15;
    const int g = (bx >> 6) & 15;
    const int n = bx >> 10;
    const int h0 = htile * TH;
    const int w0 = wtile * TW;
    const int tid = threadIdx.x;
    const int wave = tid >> 6;
    const int lane = tid & 63;

    // ---- stage pre-converted weights (straight 16B copy, layout already swizzled) ----
    {
        const u32x4* wsrc = (const u32x4*)(wks + (size_t)g * (9 * COUT_PG * 16));
        for (int i = tid; i < 9 * COUT_PG * 4; i += 256)   // 1152 x 16B
            *(u32x4*)&ws[i * 4] = wsrc[i];
    }
    if (tid < COUT_PG) bs[tid] = bias[g * COUT_PG + tid];

    // ---- stage x tile: NCHW fp32 -> [px][hi/lo ci chunks] bf16, swizzled ----
    {
        const float* xg = x + (size_t)(n * 256 + g * CIN_PG) * PLANE;
        for (int p = tid; p < NPX; p += 256) {
            int hh2 = p / XTW;
            int ww2 = p - hh2 * XTW;
            int gh = h0 + hh2 - 1;
            int gw = w0 + ww2 - 1;
            float v[16], lo[16];
            if ((unsigned)gh < HH && (unsigned)gw < WW) {
                const float* xp = xg + (size_t)gh * WW + gw;
#pragma unroll
                for (int ci = 0; ci < 16; ++ci) v[ci] = xp[(size_t)ci * PLANE];
            } else {
#pragma unroll
                for (int ci = 0; ci < 16; ++ci) v[ci] = 0.0f;
            }
#pragma unroll
            for (int ci = 0; ci < 16; ++ci) {
                unsigned ub = __builtin_bit_cast(unsigned, v[ci]);
                float hf = __builtin_bit_cast(float, ub & 0xffff0000u);
                lo[ci] = v[ci] - hf;
            }
            u32x4 c0 = {bfpack(v[0], v[1]), bfpack(v[2], v[3]), bfpack(v[4], v[5]), bfpack(v[6], v[7])};
            u32x4 c1 = {bfpack(v[8], v[9]), bfpack(v[10], v[11]), bfpack(v[12], v[13]), bfpack(v[14], v[15])};
            u32x4 c2 = {bfpack(lo[0], lo[1]), bfpack(lo[2], lo[3]), bfpack(lo[4], lo[5]), bfpack(lo[6], lo[7])};
            u32x4 c3 = {bfpack(lo[8], lo[9]), bfpack(lo[10], lo[11]), bfpack(lo[12], lo[13]), bfpack(lo[14], lo[15])};
            unsigned rot = (p >> 1) & 3;
            unsigned base = p * 16;
            *(u32x4*)&xs[base + (((0 + rot) & 3) << 2)] = c0;
            *(u32x4*)&xs[base + (((1 + rot) & 3) << 2)] = c1;
            *(u32x4*)&xs[base + (((2 + rot) & 3) << 2)] = c2;
            *(u32x4*)&xs[base + (((3 + rot) & 3) << 2)] = c3;
        }
    }
    __syncthreads();

    const int half = lane >> 5;   // ci half: 0 -> ci0-7, 1 -> ci8-15
    const int pxl = lane & 31;    // output pixel col within tile (also = co for A-frag)

    // ---- A-fragments (weights) into registers: 9 taps x {hi,lo} ----
    bf16x8 wfh[9], wfl[9];
    {
        const int co = lane & 31;
        unsigned wrot = (co >> 1) & 3;
#pragma unroll
        for (int tap = 0; tap < 9; ++tap) {
            unsigned b = (unsigned)(tap * COUT_PG + co) * 16;
            unsigned sh = ((half + wrot) & 3) << 2;
            wfh[tap] = __builtin_bit_cast(bf16x8, *(const u32x4*)&ws[b + sh]);
            wfl[tap] = __builtin_bit_cast(bf16x8, *(const u32x4*)&ws[b + (sh ^ 8)]);  // slot ^2
        }
    }

    f32x16 a0 = {}, a1 = {};
    const int r0 = wave * 2;

#pragma unroll
    for (int kh = 0; kh < 3; ++kh) {
#pragma unroll
        for (int kw = 0; kw < 3; ++kw) {
            const int tap = kh * 3 + kw;
            int p0 = (r0 + kh) * XTW + pxl + kw;
            int p1 = p0 + XTW;
            unsigned ah0 = (unsigned)p0 * 16 + (((half + ((p0 >> 1) & 3)) & 3) << 2);
            unsigned ah1 = (unsigned)p1 * 16 + (((half + ((p1 >> 1) & 3)) & 3) << 2);
            bf16x8 xh0 = __builtin_bit_cast(bf16x8, *(const u32x4*)&xs[ah0]);
            bf16x8 xl0 = __builtin_bit_cast(bf16x8, *(const u32x4*)&xs[ah0 ^ 8]);
            bf16x8 xh1 = __builtin_bit_cast(bf16x8, *(const u32x4*)&xs[ah1]);
            bf16x8 xl1 = __builtin_bit_cast(bf16x8, *(const u32x4*)&xs[ah1 ^ 8]);
            a0 = __builtin_amdgcn_mfma_f32_32x32x16_bf16(wfh[tap], xh0, a0, 0, 0, 0);
            a1 = __builtin_amdgcn_mfma_f32_32x32x16_bf16(wfh[tap], xh1, a1, 0, 0, 0);
            a0 = __builtin_amdgcn_mfma_f32_32x32x16_bf16(wfh[tap], xl0, a0, 0, 0, 0);
            a1 = __builtin_amdgcn_mfma_f32_32x32x16_bf16(wfh[tap], xl1, a1, 0, 0, 0);
            a0 = __builtin_amdgcn_mfma_f32_32x32x16_bf16(wfl[tap], xh0, a0, 0, 0, 0);
            a1 = __builtin_amdgcn_mfma_f32_32x32x16_bf16(wfl[tap], xh1, a1, 0, 0, 0);
        }
    }

    // ---- epilogue: D col = lane&31 = px (coalesced), row = (r&3)+8*(r>>2)+4*half = co ----
    float* obase = out + (size_t)(n * 512 + g * COUT_PG) * PLANE + (size_t)(h0 + r0) * WW + (w0 + pxl);
#pragma unroll
    for (int r = 0; r < 16; ++r) {
        int cor = (r & 3) + 8 * (r >> 2) + 4 * half;
        obase[(size_t)cor * PLANE] = a0[r] + bs[cor];
    }
    obase += WW;  // row r0+1
#pragma unroll
    for (int r = 0; r < 16; ++r) {
        int cor = (r & 3) + 8 * (r >> 2) + 4 * half;
        obase[(size_t)cor * PLANE] = a1[r] + bs[cor];
    }
}

extern "C" void kernel_launch(void* const* d_in, const int* in_sizes, int n_in,
                              void* d_out, int out_size, void* d_ws, size_t ws_size,
                              hipStream_t stream) {
    const float* x = (const float*)d_in[0];
    const float* w = (const float*)d_in[1];
    const float* b = (const float*)d_in[2];
    float* out = (float*)d_out;
    unsigned* wks = (unsigned*)d_ws;   // needs 294912 B
    hipLaunchKernelGGL(prep_weights, dim3(18), dim3(256), 0, stream, w, wks);
    // 16 n * 16 g * 16 h-tiles * 4 w-tiles
    hipLaunchKernelGGL(grouped_conv_mfma, dim3(16384), dim3(256), 0, stream, x, wks, b, out);
}